// Round 3
// baseline (719.315 us; speedup 1.0000x reference)
//
#include <hip/hip_runtime.h>
#include <math.h>

#define SS 1024
#define DD 64
#define BH 64

typedef __attribute__((ext_vector_type(4))) float fx4;
typedef __attribute__((ext_vector_type(8))) short sx8;
typedef __attribute__((ext_vector_type(4))) short sx4;

__device__ __forceinline__ unsigned short f2bf(float x) {
  unsigned u = __builtin_bit_cast(unsigned, x);
  u += 0x7fffu + ((u >> 16) & 1u);
  return (unsigned short)(u >> 16);
}
__device__ __forceinline__ float bf2f(unsigned short h) {
  return __builtin_bit_cast(float, ((unsigned)h) << 16);
}

// One block = 16 query rows (strip) x one bh. 256 threads = 4 waves.
// Pass 1: raw logits (registers, fx4 per 16x16 tile, wave mt owns col-tile mt
//         of each 64-col group). Split-bf16 QK^T + skew-GEMM rel-keys term.
// Softmax: register max/sum, lane butterfly over lc, LDS cross-wave combine.
// Pass 2: write normalized W, stage bf16 w (A-layout + skew band) in LDS,
//         O += w@v + wsk@RVstaged via MFMA. O scaled by 1/s at the end.
__global__ __launch_bounds__(256) void k_fused(const float* __restrict__ q,
                                               const float* __restrict__ k,
                                               const float* __restrict__ v,
                                               const float* __restrict__ RK,
                                               const float* __restrict__ RV,
                                               float* __restrict__ W,
                                               float* __restrict__ O) {
  const int it = blockIdx.x, bh = blockIdx.y;
  const int i0 = it * 16;
  const int G = (it >> 2) + 1;  // # of 64-col groups covering cols 0..i0+15

  __shared__ short smem[17280];
  __shared__ float redM[64], redS[64];
  // pass-1 layout
  short* const sQh = smem;            // 16*72
  short* const sQl = smem + 1152;     // 16*72
  short* const sKh = smem + 2304;     // 64*72
  short* const sKl = smem + 6912;     // 64*72
  short* const sR  = smem + 11520;    // 80*72 (rel-key rows m=0..79)
  // pass-2 layout (aliases pass-1; pass 1 fully done by then)
  short* const sW  = smem;            // 16*72  w in [row][col] for A-frags
  short* const sSk = smem + 1152;     // 16*104 skewed w band, m=0..95
  short* const vT  = smem + 2816;     // 64*72  v^T[d][j]
  short* const rvT = smem + 7424;     // 64*104 RVstaged^T[d][m], m=0..95

  const int t = threadIdx.x;
  const int lane = t & 63, mt = t >> 6, quad = lane >> 4, lc = lane & 15;
  const int rr0 = quad * 4;

  // zero masked W columns beyond the last group: [64G, 1024)
  {
    const int row = t >> 4, l16 = t & 15;
    float* Wr = W + ((size_t)(bh * SS + i0 + row)) * SS;
    const float4 z = {0.f, 0.f, 0.f, 0.f};
    for (int c4 = G * 16 + l16; c4 < 256; c4 += 16) *(float4*)(Wr + c4 * 4) = z;
  }

  // stage Q strip (hi/lo split)
  {
    const int row = t >> 4, c4 = (t & 15) * 4;
    const float4 x = *(const float4*)(q + ((size_t)(bh * SS + i0 + row)) * DD + c4);
    const float xs[4] = {x.x, x.y, x.z, x.w};
    sx4 h, l;
#pragma unroll
    for (int e = 0; e < 4; ++e) {
      const unsigned short hb = f2bf(xs[e]);
      h[e] = (short)hb;
      l[e] = (short)f2bf(xs[e] - bf2f(hb));
    }
    *(sx4*)&sQh[row * 72 + c4] = h;
    *(sx4*)&sQl[row * 72 + c4] = l;
  }

  fx4 L[16];

  // ---------------- pass 1: raw logits into registers ----------------
#pragma unroll
  for (int g = 0; g < 16; ++g) {
    if (g < G) {  // block-uniform
      const int j0 = g * 64;
      const int uB = j0 - i0 + 496;
      __syncthreads();
      // stage K group (hi/lo)
      for (int idx = t; idx < 1024; idx += 256) {
        const int row = idx >> 4, c4 = (idx & 15) * 4;
        const float4 x = *(const float4*)(k + ((size_t)(bh * SS + j0 + row)) * DD + c4);
        const float xs[4] = {x.x, x.y, x.z, x.w};
        sx4 h, l;
#pragma unroll
        for (int e = 0; e < 4; ++e) {
          const unsigned short hb = f2bf(xs[e]);
          h[e] = (short)hb;
          l[e] = (short)f2bf(xs[e] - bf2f(hb));
        }
        *(sx4*)&sKh[row * 72 + c4] = h;
        *(sx4*)&sKl[row * 72 + c4] = l;
      }
      // stage rel-key rows m=0..79: p = clamp(uB+m, 0, 512)
      for (int idx = t; idx < 1280; idx += 256) {
        const int mm = idx >> 4, c4 = (idx & 15) * 4;
        int p = uB + mm;
        p = p < 0 ? 0 : (p > 512 ? 512 : p);
        const float4 x = *(const float4*)(RK + (size_t)p * DD + c4);
        sx4 h;
        h[0] = (short)f2bf(x.x); h[1] = (short)f2bf(x.y);
        h[2] = (short)f2bf(x.z); h[3] = (short)f2bf(x.w);
        *(sx4*)&sR[mm * 72 + c4] = h;
      }
      __syncthreads();

      const fx4 zz = {0.f, 0.f, 0.f, 0.f};
      fx4 s1 = zz, T0 = zz, T1 = zz;
#pragma unroll
      for (int ks = 0; ks < 2; ++ks) {
        const int ko = ks * 32 + quad * 8;
        const sx8 aQh = *(const sx8*)&sQh[lc * 72 + ko];
        const sx8 aQl = *(const sx8*)&sQl[lc * 72 + ko];
        const sx8 bKh = *(const sx8*)&sKh[(mt * 16 + lc) * 72 + ko];
        const sx8 bKl = *(const sx8*)&sKl[(mt * 16 + lc) * 72 + ko];
        s1 = __builtin_amdgcn_mfma_f32_16x16x32_bf16(aQh, bKh, s1, 0, 0, 0);
        s1 = __builtin_amdgcn_mfma_f32_16x16x32_bf16(aQl, bKh, s1, 0, 0, 0);
        s1 = __builtin_amdgcn_mfma_f32_16x16x32_bf16(aQh, bKl, s1, 0, 0, 0);
        const sx8 bR0 = *(const sx8*)&sR[(mt * 16 + lc) * 72 + ko];
        const sx8 bR1 = *(const sx8*)&sR[((mt + 1) * 16 + lc) * 72 + ko];
        T0 = __builtin_amdgcn_mfma_f32_16x16x32_bf16(aQh, bR0, T0, 0, 0, 0);
        T1 = __builtin_amdgcn_mfma_f32_16x16x32_bf16(aQh, bR1, T1, 0, 0, 0);
      }
      // diagonal gather: rel[r,lc] = T[r, m=16mt+lc-r+16] (intra-quad bpermute)
      fx4 res;
#pragma unroll
      for (int e = 0; e < 4; ++e) {
        const int rr = rr0 + e;
        const int src = (lane & 48) | ((lc - rr) & 15);
        const float t0 = __shfl(T0[e], src, 64);
        const float t1 = __shfl(T1[e], src, 64);
        const float rel = (lc >= rr) ? t1 : t0;
        const bool valid = (j0 + mt * 16 + lc) <= (i0 + rr);
        res[e] = valid ? (s1[e] + rel) : -1e30f;
      }
      L[g] = res;
    }
  }

  // ---------------- softmax over registers ----------------
  float mrow[4] = {-1e30f, -1e30f, -1e30f, -1e30f};
#pragma unroll
  for (int g = 0; g < 16; ++g) {
    if (g < G) {
#pragma unroll
      for (int e = 0; e < 4; ++e) mrow[e] = fmaxf(mrow[e], L[g][e]);
    }
  }
#pragma unroll
  for (int off = 1; off <= 8; off <<= 1) {
#pragma unroll
    for (int e = 0; e < 4; ++e) mrow[e] = fmaxf(mrow[e], __shfl_xor(mrow[e], off, 64));
  }
  if (lc == 0) {
#pragma unroll
    for (int e = 0; e < 4; ++e) redM[mt * 16 + rr0 + e] = mrow[e];
  }
  __syncthreads();
#pragma unroll
  for (int e = 0; e < 4; ++e) {
    const int rr = rr0 + e;
    mrow[e] = fmaxf(fmaxf(redM[rr], redM[16 + rr]), fmaxf(redM[32 + rr], redM[48 + rr]));
  }
  float srow[4] = {0.f, 0.f, 0.f, 0.f};
#pragma unroll
  for (int g = 0; g < 16; ++g) {
    if (g < G) {
      fx4 x = L[g];
#pragma unroll
      for (int e = 0; e < 4; ++e) {
        const float ex = __expf(x[e] - mrow[e]);
        x[e] = ex;
        srow[e] += ex;
      }
      L[g] = x;
    }
  }
#pragma unroll
  for (int off = 1; off <= 8; off <<= 1) {
#pragma unroll
    for (int e = 0; e < 4; ++e) srow[e] += __shfl_xor(srow[e], off, 64);
  }
  if (lc == 0) {
#pragma unroll
    for (int e = 0; e < 4; ++e) redS[mt * 16 + rr0 + e] = srow[e];
  }
  __syncthreads();
  float inv[4];
#pragma unroll
  for (int e = 0; e < 4; ++e) {
    const int rr = rr0 + e;
    inv[e] = 1.f / (redS[rr] + redS[16 + rr] + redS[32 + rr] + redS[48 + rr]);
  }

  // ---------------- pass 2: write W, accumulate O ----------------
  const fx4 zz = {0.f, 0.f, 0.f, 0.f};
  fx4 accO = zz;
#pragma unroll
  for (int g = 0; g < 16; ++g) {
    if (g < G) {
      const int j0 = g * 64;
      const int uB = j0 - i0 + 496;
      __syncthreads();
      // scatter w into sW (A-layout) and sSk (skew band, zero-filled edges)
#pragma unroll
      for (int e = 0; e < 4; ++e) {
        const int rr = rr0 + e;
        const float wv = L[g][e];
        const short hb = (short)f2bf(wv);
        sW[rr * 72 + mt * 16 + lc] = hb;
        sSk[rr * 104 + mt * 16 + lc - rr + 16] = hb;  // band m in [16-rr, 79-rr]
        if (mt == 0 && lc + rr < 16) sSk[rr * 104 + lc] = 0;
        if (mt == 3) {
          sSk[rr * 104 + 80 - rr + lc] = 0;
          if (lc < rr) sSk[rr * 104 + 96 - rr + lc] = 0;
        }
        W[((size_t)(bh * SS + i0 + rr)) * SS + j0 + mt * 16 + lc] = wv * inv[e];
      }
      // stage v^T
      for (int idx = t; idx < 1024; idx += 256) {
        const int jj = idx >> 4, d4 = (idx & 15) * 4;
        const float4 x = *(const float4*)(v + ((size_t)(bh * SS + j0 + jj)) * DD + d4);
        vT[(d4 + 0) * 72 + jj] = (short)f2bf(x.x);
        vT[(d4 + 1) * 72 + jj] = (short)f2bf(x.y);
        vT[(d4 + 2) * 72 + jj] = (short)f2bf(x.z);
        vT[(d4 + 3) * 72 + jj] = (short)f2bf(x.w);
      }
      // stage RVstaged^T, m=0..95
      for (int idx = t; idx < 1536; idx += 256) {
        const int mm = idx >> 4, d4 = (idx & 15) * 4;
        int p = uB + mm;
        p = p < 0 ? 0 : (p > 512 ? 512 : p);
        const float4 x = *(const float4*)(RV + (size_t)p * DD + d4);
        rvT[(d4 + 0) * 104 + mm] = (short)f2bf(x.x);
        rvT[(d4 + 1) * 104 + mm] = (short)f2bf(x.y);
        rvT[(d4 + 2) * 104 + mm] = (short)f2bf(x.z);
        rvT[(d4 + 3) * 104 + mm] = (short)f2bf(x.w);
      }
      __syncthreads();
      // O += w @ v (K=64 over j)
#pragma unroll
      for (int ks = 0; ks < 2; ++ks) {
        const int ko = ks * 32 + quad * 8;
        const sx8 aW = *(const sx8*)&sW[lc * 72 + ko];
        const sx8 bV = *(const sx8*)&vT[(mt * 16 + lc) * 72 + ko];
        accO = __builtin_amdgcn_mfma_f32_16x16x32_bf16(aW, bV, accO, 0, 0, 0);
      }
      // O += wsk @ RVstaged (K=96 over m)
#pragma unroll
      for (int ks = 0; ks < 3; ++ks) {
        const int ko = ks * 32 + quad * 8;
        const sx8 aS = *(const sx8*)&sSk[lc * 104 + ko];
        const sx8 bR = *(const sx8*)&rvT[(mt * 16 + lc) * 104 + ko];
        accO = __builtin_amdgcn_mfma_f32_16x16x32_bf16(aS, bR, accO, 0, 0, 0);
      }
    }
  }

  // write O (row = rr0+e, d-col = 16*mt + lc), normalize by 1/s
#pragma unroll
  for (int e = 0; e < 4; ++e) {
    O[((size_t)(bh * SS + i0 + rr0 + e)) * DD + mt * 16 + lc] = accO[e] * inv[e];
  }
}

extern "C" void kernel_launch(void* const* d_in, const int* in_sizes, int n_in,
                              void* d_out, int out_size, void* d_ws, size_t ws_size,
                              hipStream_t stream) {
  const float* q = (const float*)d_in[0];
  const float* k = (const float*)d_in[1];
  const float* v = (const float*)d_in[2];
  const float* RK = (const float*)d_in[3];  // (1025,64); causal => rows 0..512
  const float* RV = (const float*)d_in[4];

  float* O = (float*)d_out;                         // (B,H,S,D)
  float* W = (float*)d_out + (size_t)BH * SS * DD;  // (B,H,S,S)

  k_fused<<<dim3(SS / 16, BH), 256, 0, stream>>>(q, k, v, RK, RV, W, O);
}